// Round 2
// baseline (576.707 us; speedup 1.0000x reference)
//
#include <hip/hip_runtime.h>
#include <hip/hip_bf16.h>

// Problem constants (match reference) — ALL float inputs/outputs are FP32.
#define T_TOK 4096
#define D_DIM 768
#define L_SPAN 10
#define H_HID 150
#define N_SPANS (T_TOK * L_SPAN)   // 40960
#define GDIM 2304                  // 3*D
#define YCOLS 640                  // 4 groups x 160 (150 + 10 zero-pad)

typedef __attribute__((ext_vector_type(8))) short bf16x8;  // 8 bf16 = 4 VGPRs
typedef __attribute__((ext_vector_type(4))) float f32x4;   // MFMA 16x16 acc

using bf16_t = __hip_bfloat16;

static __device__ __forceinline__ short f2b(float x) {
  __hip_bfloat16 h = __float2bfloat16(x);  // RNE
  short r;
  __builtin_memcpy(&r, &h, 2);
  return r;
}

// ---------------------------------------------------------------------------
// K0: build transposed, zero-padded, bf16 weight matrix in workspace.
//   Wt[640][768]: row n = output column n of the token GEMM.
//   group g = n/160, cj = n%160 (valid iff cj < 150):
//     g==0: W_a1[k][cj]             (attention FFNN layer 1)
//     g==1: W_m1[k        ][cj]     (mention W1, start-embed block)
//     g==2: W_m1[k +  768 ][cj]     (mention W1, end-embed block)
//     g==3: W_m1[k + 1536 ][cj]     (mention W1, attn-pooled block)
// ---------------------------------------------------------------------------
__global__ void prep_kernel(const float* __restrict__ W_a1,
                            const float* __restrict__ W_m1,
                            bf16_t* __restrict__ Wt) {
  const int total = YCOLS * D_DIM;
  for (int i = blockIdx.x * blockDim.x + threadIdx.x; i < total;
       i += gridDim.x * blockDim.x) {
    const int n = i / D_DIM;
    const int k = i - n * D_DIM;
    const int g = n / 160;
    const int cj = n - g * 160;
    float v = 0.f;
    if (cj < H_HID) {
      v = (g == 0) ? W_a1[k * H_HID + cj]
                   : W_m1[(k + (g - 1) * D_DIM) * H_HID + cj];
    }
    Wt[i] = __float2bfloat16(v);
  }
}

// ---------------------------------------------------------------------------
// K1: token GEMM  Y[4096][640] = E[4096][768] @ Wt^T   (fp32 in/out, bf16 MFMA)
//   Block = 16 rows; wave w handles col-strip [w*160, w*160+160) = 10 N-tiles.
//   MFMA 16x16x32 bf16. C/D layout (measured, m89): col=lane&15, row=quad*4+reg.
//   A frag: A[m=lane&15][k=quad*8+j] (fp32 loaded, converted inline to bf16).
//   B frag: B[k=quad*8+j][n=lane&15] read from transposed Wt (contiguous).
// ---------------------------------------------------------------------------
__global__ __launch_bounds__(256) void token_gemm_kernel(
    const float* __restrict__ E, const bf16_t* __restrict__ Wt,
    float* __restrict__ Y) {
  const int wave = threadIdx.x >> 6;
  const int lane = threadIdx.x & 63;
  const int m16 = lane & 15;
  const int quad = lane >> 4;
  const int rowBase = blockIdx.x * 16;
  const int cs = wave * 160;

  const float* Arow = E + (long)(rowBase + m16) * D_DIM + quad * 8;
  const bf16_t* Wq = Wt + (long)(cs + m16) * D_DIM + quad * 8;

  f32x4 acc[10];
#pragma unroll
  for (int nt = 0; nt < 10; ++nt) acc[nt] = (f32x4){0.f, 0.f, 0.f, 0.f};

  for (int kk = 0; kk < D_DIM / 32; ++kk) {
    const float4 f0 = *(const float4*)(Arow + kk * 32);
    const float4 f1 = *(const float4*)(Arow + kk * 32 + 4);
    bf16x8 a;
    a[0] = f2b(f0.x); a[1] = f2b(f0.y); a[2] = f2b(f0.z); a[3] = f2b(f0.w);
    a[4] = f2b(f1.x); a[5] = f2b(f1.y); a[6] = f2b(f1.z); a[7] = f2b(f1.w);
#pragma unroll
    for (int nt = 0; nt < 10; ++nt) {
      const bf16x8 b = *(const bf16x8*)(Wq + (long)nt * 16 * D_DIM + kk * 32);
      acc[nt] = __builtin_amdgcn_mfma_f32_16x16x32_bf16(a, b, acc[nt], 0, 0, 0);
    }
  }

#pragma unroll
  for (int nt = 0; nt < 10; ++nt) {
#pragma unroll
    for (int reg = 0; reg < 4; ++reg) {
      const int r = rowBase + quad * 4 + reg;
      Y[(long)r * YCOLS + cs + nt * 16 + m16] = acc[nt][reg];
    }
  }
}

// ---------------------------------------------------------------------------
// K2: one block per start token t (the L=10 spans starting at t).
//   Stage E rows t..t+9 and Y rows t..t+9 in LDS.
//   Wave 3: attns (relu-dot over Y group 0) -> softmax wts -> mention scores
//           (recombine Y groups 1..3 through the concat factorization).
//   Waves 0-2: write g_i rows [E[start], E[end], pooled] as float4.
// ---------------------------------------------------------------------------
__global__ __launch_bounds__(256) void span_kernel(
    const float* __restrict__ embeds, const int* __restrict__ ends,
    const float* __restrict__ Y, const float* __restrict__ b_a1,
    const float* __restrict__ W_a2, const float* __restrict__ b_a2,
    const float* __restrict__ b_m1, const float* __restrict__ W_m2,
    const float* __restrict__ b_m2, float* __restrict__ g,
    float* __restrict__ scores) {
  __shared__ float E[L_SPAN][D_DIM];     // 30720 B
  __shared__ float Ys[L_SPAN][YCOLS];    // 25600 B
  __shared__ float att[L_SPAN];
  __shared__ float wts[L_SPAN][L_SPAN];
  __shared__ int sE[L_SPAN];

  const int t = blockIdx.x;
  const int tid = threadIdx.x;

  // ---- stage (vectorized; rows clipped to T-1) ----
#pragma unroll
  for (int i = 0; i < L_SPAN; ++i) {
    const int r = min(t + i, T_TOK - 1);
    if (tid < 192)
      ((float4*)E)[i * 192 + tid] = ((const float4*)embeds)[(long)r * 192 + tid];
    if (tid < 160)
      ((float4*)Ys)[i * 160 + tid] = ((const float4*)Y)[(long)r * 160 + tid];
  }
  if (tid < L_SPAN) sE[tid] = ends[t * L_SPAN + tid];
  __syncthreads();

  // ---- wave 3: per-token attention logits ----
  if (tid >= 192) {
    const int lane = tid & 63;
#pragma unroll
    for (int i = 0; i < L_SPAN; ++i) {
      float p = 0.f;
      for (int c = lane; c < H_HID; c += 64) {
        const float h = Ys[i][c] + b_a1[c];
        p += (h > 0.f ? h : 0.f) * W_a2[c];
      }
#pragma unroll
      for (int m = 1; m <= 32; m <<= 1) p += __shfl_xor(p, m, 64);
      if (lane == 0) att[i] = p + b_a2[0];
    }
  }
  __syncthreads();

  // ---- softmax weights per span (threads 0..9) ----
  if (tid < L_SPAN) {
    const int v = sE[tid] - t + 1;  // valid positions (1..10)
    float mx = att[0];
    for (int o = 1; o < v; ++o) mx = fmaxf(mx, att[o]);
    float den = 0.f;
    for (int o = 0; o < v; ++o) den += __expf(att[o] - mx);
    const float inv = 1.f / den;
    for (int o = 0; o < L_SPAN; ++o)
      wts[tid][o] = (o < v) ? __expf(att[o] - mx) * inv : 0.f;
  }
  __syncthreads();

  if (tid < 192) {
    // ---- waves 0-2: write g_i rows (float4, coalesced) ----
    const float4* E4 = (const float4*)E;
#pragma unroll
    for (int l = 0; l < L_SPAN; ++l) {
      float4* g4 = (float4*)(g + ((long)t * L_SPAN + l) * GDIM);
      const int ie = sE[l] - t;  // 0..9
      g4[tid] = E4[tid];                 // start embed (row 0 = token t)
      g4[192 + tid] = E4[ie * 192 + tid];  // end embed
      float4 acc = {0.f, 0.f, 0.f, 0.f};
#pragma unroll
      for (int o = 0; o < L_SPAN; ++o) {
        const float w = wts[l][o];
        const float4 e = E4[o * 192 + tid];
        acc.x += w * e.x; acc.y += w * e.y; acc.z += w * e.z; acc.w += w * e.w;
      }
      g4[384 + tid] = acc;               // attn-pooled embed
    }
  } else {
    // ---- wave 3: mention scores via concat factorization ----
    const int lane = tid & 63;
#pragma unroll
    for (int l = 0; l < L_SPAN; ++l) {
      const int ie = sE[l] - t;
      float p = 0.f;
      for (int c = lane; c < H_HID; c += 64) {
        float h = Ys[0][160 + c] + Ys[ie][320 + c] + b_m1[c];
#pragma unroll
        for (int o = 0; o < L_SPAN; ++o) h += wts[l][o] * Ys[o][480 + c];
        p += (h > 0.f ? h : 0.f) * W_m2[c];
      }
#pragma unroll
      for (int m = 1; m <= 32; m <<= 1) p += __shfl_xor(p, m, 64);
      if (lane == 0) scores[t * L_SPAN + l] = p + b_m2[0];
    }
  }
}

// ---------------------------------------------------------------------------
extern "C" void kernel_launch(void* const* d_in, const int* in_sizes, int n_in,
                              void* d_out, int out_size, void* d_ws,
                              size_t ws_size, hipStream_t stream) {
  const float* embeds = (const float*)d_in[0];
  const int* starts = (const int*)d_in[1];  (void)starts;
  const int* ends = (const int*)d_in[2];
  const float* W_a1 = (const float*)d_in[3];
  const float* b_a1 = (const float*)d_in[4];
  const float* W_a2 = (const float*)d_in[5];
  const float* b_a2 = (const float*)d_in[6];
  const float* W_m1 = (const float*)d_in[7];
  const float* b_m1 = (const float*)d_in[8];
  const float* W_m2 = (const float*)d_in[9];
  const float* b_m2 = (const float*)d_in[10];

  char* ws = (char*)d_ws;
  bf16_t* Wt = (bf16_t*)ws;                       // 640*768*2  =   983,040 B
  float* Y = (float*)(ws + 983040);               // 4096*640*4 = 10,485,760 B

  float* g_out = (float*)d_out;                   // [N][2304]
  float* score_out = g_out + (long)N_SPANS * GDIM;  // [N]

  prep_kernel<<<480, 256, 0, stream>>>(W_a1, W_m1, Wt);
  token_gemm_kernel<<<T_TOK / 16, 256, 0, stream>>>(embeds, Wt, Y);
  span_kernel<<<T_TOK, 256, 0, stream>>>(embeds, ends, Y, b_a1, W_a2, b_a2,
                                         b_m1, W_m2, b_m2, g_out, score_out);
}

// Round 4
// 501.262 us; speedup vs baseline: 1.1505x; 1.1505x over previous
//
#include <hip/hip_runtime.h>
#include <hip/hip_bf16.h>

// Problem constants (match reference) — ALL float inputs/outputs are FP32.
#define T_TOK 4096
#define D_DIM 768
#define L_SPAN 10
#define H_HID 150
#define N_SPANS (T_TOK * L_SPAN)   // 40960
#define GDIM 2304                  // 3*D
#define WROWS 640                  // 4 groups x 160 (150 + 10 zero-pad)
#define YCOLS 480                  // stored Y: groups 1..3 only (attn fused)

typedef __attribute__((ext_vector_type(8))) short bf16x8;  // 8 bf16 = 4 VGPRs
typedef __attribute__((ext_vector_type(4))) float f32x4;   // native 16B vector

using bf16_t = __hip_bfloat16;

static __device__ __forceinline__ short f2b(float x) {
  __hip_bfloat16 h = __float2bfloat16(x);  // RNE
  short r;
  __builtin_memcpy(&r, &h, 2);
  return r;
}

// ---------------------------------------------------------------------------
// K0: build transposed, zero-padded, bf16 weight matrix in workspace.
//   Wt[640][768]: row n = output column n of the token GEMM.
//   group g = n/160, cj = n%160 (valid iff cj < 150):
//     g==0: W_a1[k][cj]           g==1: W_m1[k][cj] (start block)
//     g==2: W_m1[k+768][cj]       g==3: W_m1[k+1536][cj] (pooled block)
// ---------------------------------------------------------------------------
__global__ void prep_kernel(const float* __restrict__ W_a1,
                            const float* __restrict__ W_m1,
                            bf16_t* __restrict__ Wt) {
  const int total = WROWS * D_DIM;
  for (int i = blockIdx.x * blockDim.x + threadIdx.x; i < total;
       i += gridDim.x * blockDim.x) {
    const int n = i / D_DIM;
    const int k = i - n * D_DIM;
    const int g = n / 160;
    const int cj = n - g * 160;
    float v = 0.f;
    if (cj < H_HID) {
      v = (g == 0) ? W_a1[k * H_HID + cj]
                   : W_m1[(k + (g - 1) * D_DIM) * H_HID + cj];
    }
    Wt[i] = __float2bfloat16(v);
  }
}

// ---------------------------------------------------------------------------
// K1: token GEMM (fp32 in, bf16 MFMA).  Block = 16 token rows, 4 waves:
//   wave 0: cols 0..159 (attn FFNN) -> fused relu-dot epilogue -> attns[16]
//   waves 1..3: cols 160..639 -> Y[T][480] fp32
//   MFMA 16x16x32 bf16, C/D layout (m89): col=lane&15, row=quad*4+reg.
// ---------------------------------------------------------------------------
__global__ __launch_bounds__(256) void token_gemm_kernel(
    const float* __restrict__ E, const bf16_t* __restrict__ Wt,
    float* __restrict__ Y, float* __restrict__ attns,
    const float* __restrict__ b_a1, const float* __restrict__ W_a2,
    const float* __restrict__ b_a2) {
  const int wave = threadIdx.x >> 6;
  const int lane = threadIdx.x & 63;
  const int m16 = lane & 15;
  const int quad = lane >> 4;
  const int rowBase = blockIdx.x * 16;
  const int cs = wave * 160;

  const float* Arow = E + (long)(rowBase + m16) * D_DIM + quad * 8;
  const bf16_t* Wq = Wt + (long)(cs + m16) * D_DIM + quad * 8;

  f32x4 acc[10];
#pragma unroll
  for (int nt = 0; nt < 10; ++nt) acc[nt] = (f32x4){0.f, 0.f, 0.f, 0.f};

  for (int kk = 0; kk < D_DIM / 32; ++kk) {
    const f32x4 f0 = *(const f32x4*)(Arow + kk * 32);
    const f32x4 f1 = *(const f32x4*)(Arow + kk * 32 + 4);
    bf16x8 a;
    a[0] = f2b(f0.x); a[1] = f2b(f0.y); a[2] = f2b(f0.z); a[3] = f2b(f0.w);
    a[4] = f2b(f1.x); a[5] = f2b(f1.y); a[6] = f2b(f1.z); a[7] = f2b(f1.w);
#pragma unroll
    for (int nt = 0; nt < 10; ++nt) {
      const bf16x8 b = *(const bf16x8*)(Wq + (long)nt * 16 * D_DIM + kk * 32);
      acc[nt] = __builtin_amdgcn_mfma_f32_16x16x32_bf16(a, b, acc[nt], 0, 0, 0);
    }
  }

  if (wave == 0) {
    // fused attention-FFNN epilogue: attns[r] = relu(Y0[r]+b_a1)@W_a2 + b_a2
    float s[4] = {0.f, 0.f, 0.f, 0.f};
#pragma unroll
    for (int nt = 0; nt < 10; ++nt) {
      const int c = nt * 16 + m16;
      float b1c = 0.f, w2c = 0.f;
      if (c < H_HID) { b1c = b_a1[c]; w2c = W_a2[c]; }
#pragma unroll
      for (int r = 0; r < 4; ++r) {
        const float h = acc[nt][r] + b1c;
        s[r] += (h > 0.f ? h : 0.f) * w2c;
      }
    }
#pragma unroll
    for (int m = 1; m <= 8; m <<= 1) {
#pragma unroll
      for (int r = 0; r < 4; ++r) s[r] += __shfl_xor(s[r], m, 64);
    }
    if (m16 == 0) {
      const float b2f = b_a2[0];
#pragma unroll
      for (int r = 0; r < 4; ++r)
        attns[rowBase + quad * 4 + r] = s[r] + b2f;
    }
  } else {
    const int cs2 = (wave - 1) * 160;
#pragma unroll
    for (int nt = 0; nt < 10; ++nt) {
#pragma unroll
      for (int r = 0; r < 4; ++r) {
        const int row = rowBase + quad * 4 + r;
        Y[(long)row * YCOLS + cs2 + nt * 16 + m16] = acc[nt][r];
      }
    }
  }
}

// ---------------------------------------------------------------------------
// K2: one block per start token t (the L=10 spans starting at t).
//   Stage E rows t..t+9 (fp32) and Y rows t..t+9 in LDS (50.4 KB -> 3 blk/CU).
//   All 4 waves: span scores (concat factorization).  Then all 256 threads
//   write g_i rows [E[start], E[end], pooled] with nontemporal f32x4 stores.
// ---------------------------------------------------------------------------
__global__ __launch_bounds__(256) void span_kernel(
    const float* __restrict__ embeds, const int* __restrict__ ends,
    const float* __restrict__ Y, const float* __restrict__ attns,
    const float* __restrict__ b_m1, const float* __restrict__ W_m2,
    const float* __restrict__ b_m2, float* __restrict__ g,
    float* __restrict__ scores) {
  __shared__ float E[L_SPAN][D_DIM];     // 30720 B
  __shared__ float Ys[L_SPAN][YCOLS];    // 19200 B
  __shared__ float att[L_SPAN];
  __shared__ float wts[L_SPAN][L_SPAN];
  __shared__ int sE[L_SPAN];

  const int t = blockIdx.x;
  const int tid = threadIdx.x;

  // ---- stage (flat f32x4 loops; rows clipped to T-1) ----
  for (int idx = tid; idx < L_SPAN * 192; idx += 256) {
    const int i = idx / 192, d = idx - i * 192;
    const int r = min(t + i, T_TOK - 1);
    ((f32x4*)E)[idx] = ((const f32x4*)(embeds + (long)r * D_DIM))[d];
  }
  for (int idx = tid; idx < L_SPAN * 120; idx += 256) {
    const int i = idx / 120, d = idx - i * 120;
    const int r = min(t + i, T_TOK - 1);
    ((f32x4*)Ys)[idx] = ((const f32x4*)(Y + (long)r * YCOLS))[d];
  }
  if (tid < L_SPAN) {
    att[tid] = attns[min(t + tid, T_TOK - 1)];
    sE[tid] = ends[t * L_SPAN + tid];
  }
  __syncthreads();

  // ---- softmax weights per span (threads 0..9) ----
  if (tid < L_SPAN) {
    const int v = sE[tid] - t + 1;  // valid positions (1..10)
    float mx = att[0];
    for (int o = 1; o < v; ++o) mx = fmaxf(mx, att[o]);
    float den = 0.f;
    for (int o = 0; o < v; ++o) den += __expf(att[o] - mx);
    const float inv = 1.f / den;
    for (int o = 0; o < L_SPAN; ++o)
      wts[tid][o] = (o < v) ? __expf(att[o] - mx) * inv : 0.f;
  }
  __syncthreads();

  // ---- span scores: wave w handles spans w, w+4, w+8 ----
  {
    const int wave = tid >> 6, lane = tid & 63;
    for (int l = wave; l < L_SPAN; l += 4) {
      const int ie = sE[l] - t;
      float p = 0.f;
      for (int c = lane; c < H_HID; c += 64) {
        float h = Ys[0][c] + Ys[ie][160 + c] + b_m1[c];
#pragma unroll
        for (int o = 0; o < L_SPAN; ++o) h += wts[l][o] * Ys[o][320 + c];
        p += (h > 0.f ? h : 0.f) * W_m2[c];
      }
#pragma unroll
      for (int m = 1; m <= 32; m <<= 1) p += __shfl_xor(p, m, 64);
      if (lane == 0) scores[t * L_SPAN + l] = p + b_m2[0];
    }
  }

  // ---- g_i writes: all 256 threads, per-l with hoisted weights ----
  const f32x4* E4 = (const f32x4*)E;
#pragma unroll
  for (int l = 0; l < L_SPAN; ++l) {
    f32x4* g4 = (f32x4*)(g + ((long)t * L_SPAN + l) * GDIM);
    const int ie = sE[l] - t;
    float w[L_SPAN];
#pragma unroll
    for (int o = 0; o < L_SPAN; ++o) w[o] = wts[l][o];
    for (int off = tid; off < 576; off += 256) {
      f32x4 v;
      if (off < 192) {
        v = E4[off];                       // start embed (row 0 = token t)
      } else if (off < 384) {
        v = E4[ie * 192 + off - 192];      // end embed
      } else {
        const int d = off - 384;
        f32x4 a = {0.f, 0.f, 0.f, 0.f};
#pragma unroll
        for (int o = 0; o < L_SPAN; ++o) {
          const f32x4 e = E4[o * 192 + d];
          a.x += w[o] * e.x; a.y += w[o] * e.y;
          a.z += w[o] * e.z; a.w += w[o] * e.w;
        }
        v = a;                             // attn-pooled embed
      }
      __builtin_nontemporal_store(v, g4 + off);
    }
  }
}

// ---------------------------------------------------------------------------
extern "C" void kernel_launch(void* const* d_in, const int* in_sizes, int n_in,
                              void* d_out, int out_size, void* d_ws,
                              size_t ws_size, hipStream_t stream) {
  const float* embeds = (const float*)d_in[0];
  const int* ends = (const int*)d_in[2];
  const float* W_a1 = (const float*)d_in[3];
  const float* b_a1 = (const float*)d_in[4];
  const float* W_a2 = (const float*)d_in[5];
  const float* b_a2 = (const float*)d_in[6];
  const float* W_m1 = (const float*)d_in[7];
  const float* b_m1 = (const float*)d_in[8];
  const float* W_m2 = (const float*)d_in[9];
  const float* b_m2 = (const float*)d_in[10];

  char* ws = (char*)d_ws;
  bf16_t* Wt = (bf16_t*)ws;                    // 640*768*2  =   983,040 B
  float* Y = (float*)(ws + 983040);            // 4096*480*4 = 7,864,320 B
  float* attns = (float*)(ws + 983040 + 7864320);  // 16,384 B

  float* g_out = (float*)d_out;                     // [N][2304]
  float* score_out = g_out + (long)N_SPANS * GDIM;  // [N]

  prep_kernel<<<480, 256, 0, stream>>>(W_a1, W_m1, Wt);
  token_gemm_kernel<<<T_TOK / 16, 256, 0, stream>>>(embeds, Wt, Y, attns,
                                                    b_a1, W_a2, b_a2);
  span_kernel<<<T_TOK, 256, 0, stream>>>(embeds, ends, Y, attns, b_m1, W_m2,
                                         b_m2, g_out, score_out);
}